// Round 2
// baseline (548.979 us; speedup 1.0000x reference)
//
#include <hip/hip_runtime.h>
#include <cstddef>

typedef __attribute__((ext_vector_type(8))) short short8;
typedef __attribute__((ext_vector_type(4))) float f32x4;
typedef __attribute__((ext_vector_type(8))) _Float16 half8;

__device__ __forceinline__ unsigned short f2h(float f) {
    union { _Float16 h; unsigned short u; } x; x.h = (_Float16)f; return x.u;
}
__device__ __forceinline__ float h2f(unsigned short u) {
    union { unsigned short u; _Float16 h; } x; x.u = u; return (float)x.h;
}
__device__ __forceinline__ float lrelu(float v) { return v > 0.f ? v : 0.2f * v; }

// ---------------- CSR build ----------------

__global__ void count_edges_kernel(const int* __restrict__ ei, int E, int N,
                                   int* __restrict__ cnt) {
    int e = blockIdx.x * blockDim.x + threadIdx.x;
    if (e >= E + N) return;
    int d = (e < E) ? ei[E + e] : (e - E);  // self loops appended
    atomicAdd(&cnt[d], 1);
}

// single block, 1024 threads; also re-zeroes cnt for the scatter cursor.
__global__ void scan_kernel(int* __restrict__ cnt, int* __restrict__ rp, int n) {
    __shared__ int sh[1024];
    int t = threadIdx.x;
    int chunk = (n + 1023) >> 10;
    int beg = t * chunk;
    int end = beg + chunk < n ? beg + chunk : n;
    int local = 0;
    for (int i = beg; i < end; i++) local += cnt[i];
    sh[t] = local;
    __syncthreads();
    for (int off = 1; off < 1024; off <<= 1) {
        int v = (t >= off) ? sh[t - off] : 0;
        __syncthreads();
        sh[t] += v;
        __syncthreads();
    }
    int run = (t == 0) ? 0 : sh[t - 1];
    for (int i = beg; i < end; i++) {
        int c = cnt[i];
        cnt[i] = 0;
        run += c;
        rp[i + 1] = run;
    }
    if (t == 0) rp[0] = 0;
}

__global__ void scatter_edges_kernel(const int* __restrict__ ei, int E, int N,
                                     const int* __restrict__ rp, int* __restrict__ cur,
                                     int* __restrict__ csrc) {
    int e = blockIdx.x * blockDim.x + threadIdx.x;
    if (e >= E + N) return;
    int s, d;
    if (e < E) { s = ei[e]; d = ei[E + e]; } else { s = e - E; d = s; }
    int pos = rp[d] + atomicAdd(&cur[d], 1);
    csrc[pos] = s;
}

// ---------------- dtype prep ----------------

__global__ void f32_to_f16_pad4_kernel(const float* __restrict__ in,
                                       unsigned short* __restrict__ out,
                                       int rows, int cols, int padRows) {
    int i = blockIdx.x * blockDim.x + threadIdx.x;
    int total = (padRows * cols) >> 2;
    if (i >= total) return;
    int r = (i * 4) / cols;
    ushort4 o;
    if (r < rows) {
        float4 v = *(const float4*)(in + (size_t)i * 4);
        o = make_ushort4(f2h(v.x), f2h(v.y), f2h(v.z), f2h(v.w));
    } else {
        o = make_ushort4(0, 0, 0, 0);
    }
    *(ushort4*)(out + (size_t)i * 4) = o;
}

// All four weight transposes in one launch (f32 -> f16, [K,Nc] -> [Nc,K]).
__global__ void transpose_all_kernel(
    const float* __restrict__ W1, const float* __restrict__ W2,
    const float* __restrict__ Wm, const float* __restrict__ Wl,
    unsigned short* __restrict__ W1t, unsigned short* __restrict__ W2t,
    unsigned short* __restrict__ WmlT) {
    int i = blockIdx.x * blockDim.x + threadIdx.x;
    if (i < 65536) {
        int k = i >> 8, n = i & 255;
        W1t[(size_t)n * 256 + k] = f2h(W1[i]);
    } else if (i < 65536 + 131072) {
        int j = i - 65536;
        int k = j >> 9, n = j & 511;
        W2t[(size_t)n * 256 + k] = f2h(W2[j]);
    } else if (i < 65536 + 131072 + 65536) {
        int j = i - 196608;
        int k = j >> 7, n = j & 127;
        WmlT[(size_t)n * 512 + k] = f2h(Wm[j]);
    } else if (i < 65536 + 131072 + 131072) {
        int j = i - 262144;
        int k = j >> 7, n = j & 127;
        WmlT[(size_t)(128 + n) * 512 + k] = f2h(Wl[j]);
    }
}

// ---------------- f16 MFMA GEMM (software-pipelined) + al epilogue ----------------

__global__ __launch_bounds__(256) void gemm_f16_kernel(
    const unsigned short* __restrict__ A, const unsigned short* __restrict__ Bt,
    unsigned short* __restrict__ C, int M, int K, int Nc,
    float* __restrict__ al_s, float* __restrict__ al_d,
    const float* __restrict__ aslo, const float* __restrict__ adlo,
    const float* __restrict__ ashi, const float* __restrict__ adhi,
    int csplit, int Chead, int H) {
    __shared__ short As[64 * 32];
    __shared__ short Bs[128 * 32];
    __shared__ float salS[64][4];
    __shared__ float salD[64][4];
    int tid = threadIdx.x;
    int bm = blockIdx.y * 64;
    int bn = blockIdx.x * 128;
    int wave = tid >> 6, lane = tid & 63;
    int wm = (wave >> 1) * 32, wn = (wave & 1) * 64;
    int lm = lane & 15, lq = lane >> 4;

    f32x4 acc[2][4] = {};

    int c0 = tid, c1 = tid + 256;
    const unsigned short* Ap0 = A + (size_t)(bm + (c0 >> 2)) * K + (c0 & 3) * 8;
    const unsigned short* Bp0 = Bt + (size_t)(bn + (c0 >> 2)) * K + (c0 & 3) * 8;
    const unsigned short* Bp1 = Bt + (size_t)(bn + (c1 >> 2)) * K + (c1 & 3) * 8;

    short8 a0 = *(const short8*)(Ap0);
    short8 b0 = *(const short8*)(Bp0);
    short8 b1 = *(const short8*)(Bp1);

    for (int kk = 0; kk < K; kk += 32) {
        __syncthreads();           // prev iter's LDS frag reads done
        *(short8*)&As[c0 * 8] = a0;
        *(short8*)&Bs[c0 * 8] = b0;
        *(short8*)&Bs[c1 * 8] = b1;
        if (kk + 32 < K) {         // prefetch next tile BEFORE the MFMA burst
            a0 = *(const short8*)(Ap0 + kk + 32);
            b0 = *(const short8*)(Bp0 + kk + 32);
            b1 = *(const short8*)(Bp1 + kk + 32);
        }
        __syncthreads();           // this tile resident
        half8 af[2], bf[4];
#pragma unroll
        for (int t = 0; t < 2; t++)
            af[t] = *(const half8*)&As[(wm + t * 16 + lm) * 32 + lq * 8];
#pragma unroll
        for (int t = 0; t < 4; t++)
            bf[t] = *(const half8*)&Bs[(wn + t * 16 + lm) * 32 + lq * 8];
#pragma unroll
        for (int tm = 0; tm < 2; tm++)
#pragma unroll
            for (int tn = 0; tn < 4; tn++)
                acc[tm][tn] = __builtin_amdgcn_mfma_f32_16x16x32_f16(
                    af[tm], bf[tn], acc[tm][tn], 0, 0, 0);
    }

    // C store (f16)
#pragma unroll
    for (int tm = 0; tm < 2; tm++) {
#pragma unroll
        for (int r = 0; r < 4; r++) {
            int row = bm + wm + tm * 16 + lq * 4 + r;
            if (row < M) {
#pragma unroll
                for (int tn = 0; tn < 4; tn++) {
                    int col = bn + wn + tn * 16 + lm;
                    C[(size_t)row * Nc + col] = f2h(acc[tm][tn][r]);
                }
            }
        }
    }

    // attention-logit partial dots
    float asv[4], adv[4];
#pragma unroll
    for (int tn = 0; tn < 4; tn++) {
        int col = bn + wn + tn * 16 + lm;
        bool hi = col >= csplit;
        int cc = hi ? col - csplit : col;
        asv[tn] = hi ? ashi[cc] : aslo[cc];
        adv[tn] = hi ? adhi[cc] : adlo[cc];
    }
    int gb = wn >> 5;  // 0 or 2
#pragma unroll
    for (int tm = 0; tm < 2; tm++) {
#pragma unroll
        for (int r = 0; r < 4; r++) {
#pragma unroll
            for (int p = 0; p < 2; p++) {
                float s1 = acc[tm][2 * p][r] * asv[2 * p]
                         + acc[tm][2 * p + 1][r] * asv[2 * p + 1];
                float s2 = acc[tm][2 * p][r] * adv[2 * p]
                         + acc[tm][2 * p + 1][r] * adv[2 * p + 1];
#pragma unroll
                for (int off = 8; off >= 1; off >>= 1) {
                    s1 += __shfl_xor(s1, off);
                    s2 += __shfl_xor(s2, off);
                }
                if (lm == 0) {
                    int rl = wm + tm * 16 + lq * 4 + r;
                    salS[rl][gb + p] = s1;
                    salD[rl][gb + p] = s2;
                }
            }
        }
    }
    __syncthreads();
    if (tid < 64) {
        int row = bm + tid;
        if (row < M) {
            int hb = bn / Chead;       // first head in this col-block
            int HB = 128 / Chead;      // heads per col-block (1, 2, or 4)
            int GH = Chead >> 5;       // 32-col groups per head
            for (int i = 0; i < HB; i++) {
                float ss = 0.f, sd = 0.f;
                for (int j = 0; j < GH; j++) {
                    ss += salS[tid][i * GH + j];
                    sd += salD[tid][i * GH + j];
                }
                al_s[(size_t)row * H + hb + i] = ss;
                al_d[(size_t)row * H + hb + i] = sd;
            }
        }
    }
}

// ---------------- per-node softmax -> alphaT[H][E] (f16) ----------------
// 4 waves/block, one node per wave; lane-per-edge butterfly softmax (no LDS).

template <int H4>
__global__ __launch_bounds__(256) void alpha_kernel(
    const int* __restrict__ rp, const int* __restrict__ csrc,
    const float* __restrict__ al_s, const float* __restrict__ al_d,
    unsigned short* __restrict__ alphaT, int Ep, int N) {
    const int H = 4 * H4;
    int wv = threadIdx.x >> 6;
    int lane = threadIdx.x & 63;
    int n = blockIdx.x * 4 + wv;
    if (n >= N) return;
    int beg = rp[n], end = rp[n + 1];
    int deg = end - beg;

    float ad[H];
#pragma unroll
    for (int g = 0; g < H4; g++)
        *(float4*)&ad[g * 4] = *(const float4*)(al_d + (size_t)n * H + g * 4);

    if (deg <= 64) {
        bool act = lane < deg;
        int s = act ? csrc[beg + lane] : 0;
        float v[H], m[H], ex[H], sum[H];
#pragma unroll
        for (int g = 0; g < H4; g++) {
            float4 as = *(const float4*)(al_s + (size_t)s * H + g * 4);
            v[g * 4 + 0] = lrelu(as.x + ad[g * 4 + 0]);
            v[g * 4 + 1] = lrelu(as.y + ad[g * 4 + 1]);
            v[g * 4 + 2] = lrelu(as.z + ad[g * 4 + 2]);
            v[g * 4 + 3] = lrelu(as.w + ad[g * 4 + 3]);
        }
#pragma unroll
        for (int j = 0; j < H; j++) m[j] = act ? v[j] : -3.402823466e38f;
#pragma unroll
        for (int off = 32; off >= 1; off >>= 1)
#pragma unroll
            for (int j = 0; j < H; j++) m[j] = fmaxf(m[j], __shfl_xor(m[j], off));
#pragma unroll
        for (int j = 0; j < H; j++) {
            ex[j] = act ? __expf(v[j] - m[j]) : 0.f;
            sum[j] = ex[j];
        }
#pragma unroll
        for (int off = 32; off >= 1; off >>= 1)
#pragma unroll
            for (int j = 0; j < H; j++) sum[j] += __shfl_xor(sum[j], off);
        if (act) {
#pragma unroll
            for (int j = 0; j < H; j++)
                alphaT[(size_t)j * Ep + beg + lane] = f2h(ex[j] / (sum[j] + 1e-16f));
        }
    } else {
        // general path (deg > 64): strided stats with recompute
        float m[H], sum[H];
#pragma unroll
        for (int j = 0; j < H; j++) m[j] = -3.402823466e38f;
        for (int e = beg + lane; e < end; e += 64) {
            int s = csrc[e];
#pragma unroll
            for (int g = 0; g < H4; g++) {
                float4 as = *(const float4*)(al_s + (size_t)s * H + g * 4);
                m[g * 4 + 0] = fmaxf(m[g * 4 + 0], lrelu(as.x + ad[g * 4 + 0]));
                m[g * 4 + 1] = fmaxf(m[g * 4 + 1], lrelu(as.y + ad[g * 4 + 1]));
                m[g * 4 + 2] = fmaxf(m[g * 4 + 2], lrelu(as.z + ad[g * 4 + 2]));
                m[g * 4 + 3] = fmaxf(m[g * 4 + 3], lrelu(as.w + ad[g * 4 + 3]));
            }
        }
#pragma unroll
        for (int off = 32; off >= 1; off >>= 1)
#pragma unroll
            for (int j = 0; j < H; j++) m[j] = fmaxf(m[j], __shfl_xor(m[j], off));
#pragma unroll
        for (int j = 0; j < H; j++) sum[j] = 0.f;
        for (int e = beg + lane; e < end; e += 64) {
            int s = csrc[e];
#pragma unroll
            for (int g = 0; g < H4; g++) {
                float4 as = *(const float4*)(al_s + (size_t)s * H + g * 4);
                sum[g * 4 + 0] += __expf(lrelu(as.x + ad[g * 4 + 0]) - m[g * 4 + 0]);
                sum[g * 4 + 1] += __expf(lrelu(as.y + ad[g * 4 + 1]) - m[g * 4 + 1]);
                sum[g * 4 + 2] += __expf(lrelu(as.z + ad[g * 4 + 2]) - m[g * 4 + 2]);
                sum[g * 4 + 3] += __expf(lrelu(as.w + ad[g * 4 + 3]) - m[g * 4 + 3]);
            }
        }
#pragma unroll
        for (int off = 32; off >= 1; off >>= 1)
#pragma unroll
            for (int j = 0; j < H; j++) sum[j] += __shfl_xor(sum[j], off);
        float r[H];
#pragma unroll
        for (int j = 0; j < H; j++) r[j] = 1.0f / (sum[j] + 1e-16f);
        for (int e = beg + lane; e < end; e += 64) {
            int s = csrc[e];
#pragma unroll
            for (int g = 0; g < H4; g++) {
                float4 as = *(const float4*)(al_s + (size_t)s * H + g * 4);
                alphaT[(size_t)(g * 4 + 0) * Ep + e] =
                    f2h(__expf(lrelu(as.x + ad[g * 4 + 0]) - m[g * 4 + 0]) * r[g * 4 + 0]);
                alphaT[(size_t)(g * 4 + 1) * Ep + e] =
                    f2h(__expf(lrelu(as.y + ad[g * 4 + 1]) - m[g * 4 + 1]) * r[g * 4 + 1]);
                alphaT[(size_t)(g * 4 + 2) * Ep + e] =
                    f2h(__expf(lrelu(as.z + ad[g * 4 + 2]) - m[g * 4 + 2]) * r[g * 4 + 2]);
                alphaT[(size_t)(g * 4 + 3) * Ep + e] =
                    f2h(__expf(lrelu(as.w + ad[g * 4 + 3]) - m[g * 4 + 3]) * r[g * 4 + 3]);
            }
        }
    }
}

// ---------------- channel-sliced aggregation (XCD-pinned slices) ----------------
// Grid = NS * ceil(N/4); slice = blockIdx % NS so consecutive blocks (which
// round-robin across XCDs) carry distinct channel slices: each XCD's L2 only
// caches HC/NS columns of h (<= 4 MiB). Per wave: one node; lanes split as
// 8 edge-groups x 8 lanes x 8 ch -> 8 edges in flight per VMEM instruction.
// f32 accumulate, butterfly-reduce across edge groups, lanes eg==0 store.

template <int NS, int HC, int C>
__global__ __launch_bounds__(256) void agg_concat_kernel(
    const int* __restrict__ rp, const int* __restrict__ csrc,
    const unsigned short* __restrict__ alphaT, int Ep,
    const unsigned short* __restrict__ h, const float* __restrict__ bias,
    unsigned short* __restrict__ out, int N) {
    int wv = threadIdx.x >> 6;
    int lane = threadIdx.x & 63;
    int bs = blockIdx.x % NS;            // channel slice (XCD-pinned)
    int n = (blockIdx.x / NS) * 4 + wv;
    if (n >= N) return;
    int beg = rp[n], end = rp[n + 1];
    int eg = lane >> 3;                  // edge sub-group 0..7
    int cg = lane & 7;                   // 8 ch per lane
    int ch = bs * 64 + cg * 8;
    const unsigned short* at = alphaT + (size_t)((bs * 64) / C) * Ep;
    const unsigned short* hp = h + ch;
    float acc[8] = {};
    for (int t = beg + eg; t < end; t += 8) {
        int s = csrc[t];
        float a = h2f(at[t]);
        half8 hv = *(const half8*)(hp + (size_t)s * HC);
#pragma unroll
        for (int i = 0; i < 8; i++) acc[i] += a * (float)hv[i];
    }
#pragma unroll
    for (int off = 8; off <= 32; off <<= 1)
#pragma unroll
        for (int i = 0; i < 8; i++) acc[i] += __shfl_xor(acc[i], off);
    if (eg == 0) {
        short8 o;
#pragma unroll
        for (int i = 0; i < 8; i++)
            o[i] = (short)f2h(fmaxf(acc[i] + bias[ch + i], 0.f));
        *(short8*)(out + (size_t)n * HC + ch) = o;
    }
}

// Layers 3+4: HC=256 = 8 heads x 32 ch; slice o covers one output (4 heads,
// 128 ch). 4 edge-groups x 16 lanes x 8 ch. Butterfly over lane bits 4,5
// (edge groups) and 2,3 (head mean); lanes 0..3 write f32 [N,32] + bias.

__global__ __launch_bounds__(256) void agg_mean_kernel(
    const int* __restrict__ rp, const int* __restrict__ csrc,
    const unsigned short* __restrict__ alphaT, int Ep,
    const unsigned short* __restrict__ h,
    const float* __restrict__ bias1, const float* __restrict__ bias2,
    float* __restrict__ out1, float* __restrict__ out2, int N) {
    int wv = threadIdx.x >> 6;
    int lane = threadIdx.x & 63;
    int o = blockIdx.x & 1;              // output slice (XCD-spread)
    int n = (blockIdx.x >> 1) * 4 + wv;
    if (n >= N) return;
    int beg = rp[n], end = rp[n + 1];
    int eg = lane >> 4;                  // edge sub-group 0..3
    int cg = lane & 15;                  // 8 ch per lane over 128-ch slice
    int ch = o * 128 + cg * 8;
    const unsigned short* at = alphaT + (size_t)(o * 4 + (cg >> 2)) * Ep;
    const unsigned short* hp = h + ch;
    float acc[8] = {};
    for (int t = beg + eg; t < end; t += 4) {
        int s = csrc[t];
        float a = h2f(at[t]);
        half8 hv = *(const half8*)(hp + (size_t)s * 256);
#pragma unroll
        for (int i = 0; i < 8; i++) acc[i] += a * (float)hv[i];
    }
    // sum over edge groups (bits 4,5) and over the 4 heads (bits 2,3)
#pragma unroll
    for (int off = 4; off <= 32; off <<= 1)
#pragma unroll
        for (int i = 0; i < 8; i++) acc[i] += __shfl_xor(acc[i], off);
    if (lane < 4) {                      // eg==0, cg<4: 4 lanes x 8 ch = 32 out
        const float* bb = o ? bias2 : bias1;
        float* op = o ? out2 : out1;
        int wc = lane * 8;
        float4 r0, r1;
        r0.x = acc[0] * 0.25f + bb[wc + 0];
        r0.y = acc[1] * 0.25f + bb[wc + 1];
        r0.z = acc[2] * 0.25f + bb[wc + 2];
        r0.w = acc[3] * 0.25f + bb[wc + 3];
        r1.x = acc[4] * 0.25f + bb[wc + 4];
        r1.y = acc[5] * 0.25f + bb[wc + 5];
        r1.z = acc[6] * 0.25f + bb[wc + 6];
        r1.w = acc[7] * 0.25f + bb[wc + 7];
        *(float4*)(op + (size_t)n * 32 + wc) = r0;
        *(float4*)(op + (size_t)n * 32 + wc + 4) = r1;
    }
}

// ---------------- orchestration ----------------

extern "C" void kernel_launch(void* const* d_in, const int* in_sizes, int n_in,
                              void* d_out, int out_size, void* d_ws, size_t ws_size,
                              hipStream_t stream) {
    (void)n_in; (void)out_size; (void)ws_size;
    const float* x   = (const float*)d_in[0];
    const int*   ei  = (const int*)d_in[1];
    const float* W1  = (const float*)d_in[2];
    const float* as1 = (const float*)d_in[3];
    const float* ad1 = (const float*)d_in[4];
    const float* b1  = (const float*)d_in[5];
    const float* W2  = (const float*)d_in[6];
    const float* as2 = (const float*)d_in[7];
    const float* ad2 = (const float*)d_in[8];
    const float* b2  = (const float*)d_in[9];
    const float* Wm  = (const float*)d_in[10];
    const float* a_sm = (const float*)d_in[11];
    const float* a_dm = (const float*)d_in[12];
    const float* bm  = (const float*)d_in[13];
    const float* Wl  = (const float*)d_in[14];
    const float* a_sl = (const float*)d_in[15];
    const float* a_dl = (const float*)d_in[16];
    const float* bl  = (const float*)d_in[17];
    float* outp = (float*)d_out;

    const int N  = in_sizes[0] / 256;   // 30000
    const int E  = in_sizes[1] / 2;     // 480000
    const int ET = E + N;               // with self loops
    const int gM128 = (N + 127) / 128;  // 235
    const int Mp = gM128 * 128;         // 30080 (padded rows)
    const int gM64 = (N + 63) / 64;     // 469

    auto align_up = [](size_t v) { return (v + 255) & ~(size_t)255; };
    char* w = (char*)d_ws;
    int* row_ptr = (int*)w;  w += align_up((size_t)(N + 1) * 4);
    int* cnt     = (int*)w;  w += align_up((size_t)N * 4);
    int* csrc    = (int*)w;  w += align_up((size_t)ET * 4);
    float* al_s  = (float*)w; w += align_up((size_t)N * 8 * 4);
    float* al_d  = (float*)w; w += align_up((size_t)N * 8 * 4);
    unsigned short* xb   = (unsigned short*)w; w += align_up((size_t)Mp * 256 * 2);
    unsigned short* W1t  = (unsigned short*)w; w += align_up((size_t)256 * 256 * 2);
    unsigned short* W2t  = (unsigned short*)w; w += align_up((size_t)512 * 256 * 2);
    unsigned short* WmlT = (unsigned short*)w; w += align_up((size_t)256 * 512 * 2);
    unsigned short* bufH = (unsigned short*)w; w += align_up((size_t)Mp * 512 * 2);
    unsigned short* bufO = (unsigned short*)w; w += align_up((size_t)Mp * 512 * 2);
    // alphaT aliases xb: xb (layer-1 GEMM input) is dead once the first GEMM
    // has run, and alphaT's first write is stream-ordered after it.
    // 8*ET*2 = 8.16 MB <= Mp*256*2 = 15.4 MB. Keeps ws footprint identical
    // to the last passing version.
    unsigned short* alphaT = xb;

    // ---- CSR build ----
    int gzE = (ET + 255) / 256;
    hipMemsetAsync(cnt, 0, (size_t)N * 4, stream);
    count_edges_kernel<<<gzE, 256, 0, stream>>>(ei, E, N, cnt);
    scan_kernel<<<1, 1024, 0, stream>>>(cnt, row_ptr, N);   // re-zeroes cnt
    scatter_edges_kernel<<<gzE, 256, 0, stream>>>(ei, E, N, row_ptr, cnt, csrc);

    // ---- dtype prep ----
    f32_to_f16_pad4_kernel<<<((Mp * 256 / 4) + 255) / 256, 256, 0, stream>>>(
        x, xb, N, 256, Mp);
    transpose_all_kernel<<<(393216 + 255) / 256, 256, 0, stream>>>(
        W1, W2, Wm, Wl, W1t, W2t, WmlT);

    int gF = (N + 3) / 4;  // 7500

    // ---- Layer 1: GAT(256 -> 4x64, concat) + ReLU ----
    gemm_f16_kernel<<<dim3(2, gM64), 256, 0, stream>>>(
        xb, W1t, bufH, N, 256, 256, al_s, al_d, as1, ad1, as1, ad1, 256, 64, 4);
    alpha_kernel<1><<<gF, 256, 0, stream>>>(row_ptr, csrc, al_s, al_d, alphaT, ET, N);
    agg_concat_kernel<4, 256, 64><<<4 * gF, 256, 0, stream>>>(
        row_ptr, csrc, alphaT, ET, bufH, b1, bufO, N);

    // ---- Layer 2: GAT(256 -> 4x128, concat) + ReLU ----
    gemm_f16_kernel<<<dim3(4, gM64), 256, 0, stream>>>(
        bufO, W2t, bufH, N, 256, 512, al_s, al_d, as2, ad2, as2, ad2, 512, 128, 4);
    alpha_kernel<1><<<gF, 256, 0, stream>>>(row_ptr, csrc, al_s, al_d, alphaT, ET, N);
    agg_concat_kernel<8, 512, 128><<<8 * gF, 256, 0, stream>>>(
        row_ptr, csrc, alphaT, ET, bufH, b2, bufO, N);

    // ---- Layers 3+4 batched: GAT(512 -> 8x32, mean per 4-head group) ----
    gemm_f16_kernel<<<dim3(2, gM64), 256, 0, stream>>>(
        bufO, WmlT, bufH, N, 512, 256, al_s, al_d, a_sm, a_dm, a_sl, a_dl, 128, 32, 8);
    alpha_kernel<2><<<gF, 256, 0, stream>>>(row_ptr, csrc, al_s, al_d, alphaT, ET, N);
    agg_mean_kernel<<<2 * gF, 256, 0, stream>>>(
        row_ptr, csrc, alphaT, ET, bufH, bm, bl, outp, outp + (size_t)N * 32, N);
}